// Round 1
// baseline (203.258 us; speedup 1.0000x reference)
//
#include <hip/hip_runtime.h>
#include <stdint.h>
#include <stddef.h>

// ---------------------------------------------------------------------------
// ModuleGARO: corr(256x256 per bt, 512 bt) -> [512,65536]@[65536,256] GEMM ->
// BN/ReLU chain -> sigmoid QK attention scale.
// ws layout (bytes):
//   WT   bf16 256x65536   33,554,432
//   fc   bf16 512x65536   67,108,864
//   P    f32  64x512x256  33,554,432
//   a1,h1,a2,h2,a3,h3,a4,Hh  f32 512x256 each  8x524,288
//   q    f32  8x256       8,192
// total ~132 MB
// ---------------------------------------------------------------------------

typedef short short8 __attribute__((ext_vector_type(8)));
typedef float f32x4 __attribute__((ext_vector_type(4)));

#define DEV __device__ __forceinline__

DEV unsigned short f2bf(float f){
  union { float f; unsigned u; } v; v.f = f;
  unsigned r = v.u + 0x7FFFu + ((v.u >> 16) & 1u);   // RNE
  return (unsigned short)(r >> 16);
}
DEV float bf2f(unsigned short b){
  union { unsigned u; float f; } v; v.u = ((unsigned)b) << 16;
  return v.f;
}
DEV void gload_lds16(const void* g, void* l){
  __builtin_amdgcn_global_load_lds(
      (const __attribute__((address_space(1))) unsigned int*)g,
      (__attribute__((address_space(3))) unsigned int*)l, 16, 0, 0);
}

// ---------------------------------------------------------------------------
// k_wt: WT[o][k] = bf16(m1W[k][o]); 64x64 tiles via LDS transpose.
// ---------------------------------------------------------------------------
__global__ __launch_bounds__(256) void k_wt(const float* __restrict__ W,
                                            unsigned short* __restrict__ WT){
  __shared__ float tile[64][65];
  const int k0 = blockIdx.x * 64;
  const int o0 = blockIdx.y * 64;
  const int tr = threadIdx.x >> 6;   // 0..3
  const int tc = threadIdx.x & 63;
  #pragma unroll
  for (int i = 0; i < 16; ++i){
    int kr = i*4 + tr;
    tile[kr][tc] = W[(size_t)(k0+kr)*256 + o0 + tc];
  }
  __syncthreads();
  #pragma unroll
  for (int i = 0; i < 16; ++i){
    int orow = i*4 + tr;
    WT[(size_t)(o0+orow)*65536 + k0 + tc] = f2bf(tile[tc][orow]);
  }
}

// ---------------------------------------------------------------------------
// k_corr: one block per bt. corr = (y^T y) * rs_i * rs_j, clip [-1,1], bf16.
//   yT[256][72] bf16 (144B rows, 16B aligned), rs[256] f32,
//   stg[4][64*40] bf16 per-wave output staging for coalesced 16B stores.
// ---------------------------------------------------------------------------
__global__ __launch_bounds__(256) void k_corr(const float* __restrict__ x,
                                              unsigned short* __restrict__ fc){
  __shared__ unsigned short yT[256*72];
  __shared__ float rs[256];
  __shared__ unsigned short stg[4][64*40];
  const int bt = blockIdx.x;
  const float* xb = x + (size_t)bt * 16384;   // 64 samples x 256 vars
  const int i = threadIdx.x;                  // column (variable) index

  float sum = 0.f;
  #pragma unroll 8
  for (int s = 0; s < 64; ++s) sum += xb[s*256 + i];
  const float mean = sum * (1.f/64.f);

  float ss = 0.f;
  unsigned int* yT32 = (unsigned int*)yT;
  #pragma unroll 4
  for (int s = 0; s < 64; s += 2){
    float v0 = xb[s*256 + i] - mean;
    float v1 = xb[(s+1)*256 + i] - mean;
    unsigned short b0 = f2bf(v0), b1 = f2bf(v1);
    float r0 = bf2f(b0), r1 = bf2f(b1);
    ss += r0*r0 + r1*r1;                      // sumsq of the *rounded* values
    yT32[(i*72 + s) >> 1] = (unsigned)b0 | ((unsigned)b1 << 16);
  }
  rs[i] = rsqrtf(ss);
  __syncthreads();

  const int w   = threadIdx.x >> 6;           // wave 0..3 -> rows w*64..w*64+63
  const int l   = threadIdx.x & 63;
  const int l15 = l & 15, lg = l >> 4;

  // row fragments (A): yT[row][k], 8 contiguous bf16 per lane
  short8 RF[4][2];
  #pragma unroll
  for (int rt = 0; rt < 4; ++rt){
    int row = w*64 + rt*16 + l15;
    #pragma unroll
    for (int ks = 0; ks < 2; ++ks)
      RF[rt][ks] = *(const short8*)&yT[row*72 + ks*32 + lg*8];
  }
  float rrow[4][4];
  #pragma unroll
  for (int rt = 0; rt < 4; ++rt)
    #pragma unroll
    for (int r = 0; r < 4; ++r)
      rrow[rt][r] = rs[w*64 + rt*16 + lg*4 + r];

  unsigned short* sg = stg[w];
  for (int cc = 0; cc < 8; ++cc){             // 8 chunks of 32 output cols
    short8 CF[2][2];
    #pragma unroll
    for (int ct = 0; ct < 2; ++ct){
      int col = cc*32 + ct*16 + l15;
      #pragma unroll
      for (int ks = 0; ks < 2; ++ks)
        CF[ct][ks] = *(const short8*)&yT[col*72 + ks*32 + lg*8];
    }
    f32x4 acc[4][2];
    #pragma unroll
    for (int rt = 0; rt < 4; ++rt)
      #pragma unroll
      for (int ct = 0; ct < 2; ++ct)
        acc[rt][ct] = (f32x4){0.f,0.f,0.f,0.f};
    #pragma unroll
    for (int ks = 0; ks < 2; ++ks)
      #pragma unroll
      for (int rt = 0; rt < 4; ++rt)
        #pragma unroll
        for (int ct = 0; ct < 2; ++ct)
          acc[rt][ct] = __builtin_amdgcn_mfma_f32_16x16x32_bf16(
              RF[rt][ks], CF[ct][ks], acc[rt][ct], 0, 0, 0);

    float rc[2] = { rs[cc*32 + l15], rs[cc*32 + 16 + l15] };
    #pragma unroll
    for (int rt = 0; rt < 4; ++rt)
      #pragma unroll
      for (int ct = 0; ct < 2; ++ct)
        #pragma unroll
        for (int r = 0; r < 4; ++r){
          float v = acc[rt][ct][r] * rrow[rt][r] * rc[ct];
          v = fminf(fmaxf(v, -1.f), 1.f);
          sg[(rt*16 + lg*4 + r)*40 + ct*16 + l15] = f2bf(v);
        }
    // wave-private staging: DS pipe is in-order per wave, no barrier needed
    #pragma unroll
    for (int idx = 0; idx < 4; ++idx){
      int c = idx*64 + l;
      int rowL = c >> 2, ch = c & 3;
      short8 v = *(const short8*)&sg[rowL*40 + ch*8];
      *(short8*)&fc[(size_t)bt*65536 + (size_t)(w*64 + rowL)*256 + cc*32 + ch*8] = v;
    }
  }
}

// ---------------------------------------------------------------------------
// k_gemm: [512,65536]bf16 @ WT^T -> split-K fp32 partials.
// grid (64 ksplit, 4 Mtiles, 2 Ntiles); 128x128 tile, BK=64, XOR chunk-swizzle
// applied on the GLOBAL source address (LDS dest stays linear for gload_lds).
// ---------------------------------------------------------------------------
__global__ __launch_bounds__(256) void k_gemm(const unsigned short* __restrict__ fc,
                                              const unsigned short* __restrict__ WT,
                                              float* __restrict__ P){
  __shared__ unsigned short Al[128*64];
  __shared__ unsigned short Bl[128*64];
  const int ksb = blockIdx.x;
  const int m0  = blockIdx.y * 128;
  const int n0  = blockIdx.z * 128;
  const int k0  = ksb * 1024;
  const int t   = threadIdx.x;
  const int w = t >> 6, l = t & 63, l15 = l & 15, lg = l >> 4;
  const int wrow = (w >> 1) * 64, wcol = (w & 1) * 64;

  f32x4 acc[4][4];
  #pragma unroll
  for (int a = 0; a < 4; ++a)
    #pragma unroll
    for (int b = 0; b < 4; ++b) acc[a][b] = (f32x4){0.f,0.f,0.f,0.f};

  for (int kt = 0; kt < 16; ++kt){
    const int kk = k0 + kt*64;
    #pragma unroll
    for (int i2 = 0; i2 < 4; ++i2){
      int c = i2*256 + t;
      int row = c >> 3, ch = c & 7;
      int sch = ch ^ (row & 7);
      gload_lds16(fc + (size_t)(m0+row)*65536 + kk + sch*8, &Al[c*8]);
    }
    #pragma unroll
    for (int i2 = 0; i2 < 4; ++i2){
      int c = i2*256 + t;
      int row = c >> 3, ch = c & 7;
      int sch = ch ^ (row & 7);
      gload_lds16(WT + (size_t)(n0+row)*65536 + kk + sch*8, &Bl[c*8]);
    }
    __syncthreads();
    #pragma unroll
    for (int ks = 0; ks < 2; ++ks){
      short8 af[4], bf[4];
      #pragma unroll
      for (int rt = 0; rt < 4; ++rt){
        int row = wrow + rt*16 + l15;
        int pch = (ks*4 + lg) ^ (row & 7);
        af[rt] = *(const short8*)&Al[row*64 + pch*8];
      }
      #pragma unroll
      for (int ct = 0; ct < 4; ++ct){
        int row = wcol + ct*16 + l15;
        int pch = (ks*4 + lg) ^ (row & 7);
        bf[ct] = *(const short8*)&Bl[row*64 + pch*8];
      }
      #pragma unroll
      for (int rt = 0; rt < 4; ++rt)
        #pragma unroll
        for (int ct = 0; ct < 4; ++ct)
          acc[rt][ct] = __builtin_amdgcn_mfma_f32_16x16x32_bf16(
              af[rt], bf[ct], acc[rt][ct], 0, 0, 0);
    }
    __syncthreads();
  }

  float* Pb = P + (size_t)ksb * 131072;
  #pragma unroll
  for (int rt = 0; rt < 4; ++rt)
    #pragma unroll
    for (int ct = 0; ct < 4; ++ct)
      #pragma unroll
      for (int r = 0; r < 4; ++r){
        int row = m0 + wrow + rt*16 + lg*4 + r;
        int col = n0 + wcol + ct*16 + l15;
        Pb[(size_t)row*256 + col] = acc[rt][ct][r];
      }
}

// ---------------------------------------------------------------------------
// k_reduce: a[bt][j] = sum_ks P[ks][bt][j] + bias[j]
// ---------------------------------------------------------------------------
__global__ __launch_bounds__(256) void k_reduce(const float* __restrict__ P,
                                                const float* __restrict__ bias,
                                                float* __restrict__ a){
  const int bt = blockIdx.x, j = threadIdx.x;
  float s = 0.f;
  #pragma unroll 8
  for (int ks = 0; ks < 64; ++ks) s += P[(size_t)ks*131072 + bt*256 + j];
  a[bt*256 + j] = s + bias[j];
}

// ---------------------------------------------------------------------------
// k_bn: per-column batch stats over 512 rows (biased var), apply + ReLU.
// block = one column j; 256 threads, 2 rows each.
// ---------------------------------------------------------------------------
__global__ __launch_bounds__(256) void k_bn(const float* __restrict__ a,
                                            const float* __restrict__ g,
                                            const float* __restrict__ beta,
                                            float* __restrict__ h){
  const int j = blockIdx.x, t = threadIdx.x;
  float v0 = a[t*256 + j], v1 = a[(t+256)*256 + j];
  float s = v0 + v1, q = v0*v0 + v1*v1;
  #pragma unroll
  for (int o = 1; o < 64; o <<= 1){ s += __shfl_xor(s, o); q += __shfl_xor(q, o); }
  __shared__ float sw[4], qw[4];
  if ((t & 63) == 0){ sw[t >> 6] = s; qw[t >> 6] = q; }
  __syncthreads();
  float S = sw[0] + sw[1] + sw[2] + sw[3];
  float Q = qw[0] + qw[1] + qw[2] + qw[3];
  float mu  = S * (1.f/512.f);
  float var = Q * (1.f/512.f) - mu*mu;
  float sc = g[j] * rsqrtf(var + 1e-5f);
  float sh = beta[j] - mu * sc;
  h[t*256 + j]       = fmaxf(v0*sc + sh, 0.f);
  h[(t+256)*256 + j] = fmaxf(v1*sc + sh, 0.f);
}

// ---------------------------------------------------------------------------
// k_sg: small GEMM a = [x | es?] @ W + bias. block = 2 bt rows, thread = col.
// ---------------------------------------------------------------------------
template<int KK, bool CAT>
__global__ __launch_bounds__(256) void k_sg(const float* __restrict__ xin,
                                            const float* __restrict__ es,
                                            const float* __restrict__ W,
                                            const float* __restrict__ bias,
                                            float* __restrict__ aout){
  __shared__ float xr[2][KK];
  const int bt0 = blockIdx.x * 2;
  const int j = threadIdx.x;
  #pragma unroll
  for (int r = 0; r < 2; ++r){
    xr[r][j] = xin[(bt0+r)*256 + j];
    if constexpr (CAT) xr[r][256 + j] = es[(bt0 >> 6)*256 + j];
  }
  __syncthreads();
  float a0 = 0.f, a1 = 0.f;
  #pragma unroll 4
  for (int k = 0; k < KK; ++k){
    float wv = W[k*256 + j];
    a0 += xr[0][k] * wv;
    a1 += xr[1][k] * wv;
  }
  aout[bt0*256 + j]     = a0 + bias[j];
  aout[(bt0+1)*256 + j] = a1 + bias[j];
}

// ---------------------------------------------------------------------------
// k_qmean: per b: Hm = mean_t Hh[b,t,:]; q = Hm @ qW + qb
// ---------------------------------------------------------------------------
__global__ __launch_bounds__(256) void k_qmean(const float* __restrict__ Hh,
                                               const float* __restrict__ qW,
                                               const float* __restrict__ qb,
                                               float* __restrict__ q){
  __shared__ float hm[256];
  const int b = blockIdx.x, j = threadIdx.x;
  float s = 0.f;
  #pragma unroll 8
  for (int tt = 0; tt < 64; ++tt) s += Hh[((b<<6)+tt)*256 + j];
  hm[j] = s * (1.f/64.f);
  __syncthreads();
  float a = 0.f;
  #pragma unroll 4
  for (int k = 0; k < 256; ++k) a += hm[k] * qW[k*256 + j];
  q[b*256 + j] = a + qb[j];
}

// ---------------------------------------------------------------------------
// k_att: per bt: kvec = Hh_row @ kW + kb; s = dot(q_b,kvec)/16;
//        out = Hh_row * sigmoid(s)
// ---------------------------------------------------------------------------
__global__ __launch_bounds__(256) void k_att(const float* __restrict__ Hh,
                                             const float* __restrict__ kW,
                                             const float* __restrict__ kb,
                                             const float* __restrict__ q,
                                             float* __restrict__ out){
  __shared__ float hr[256];
  __shared__ float pw[4];
  const int bt = blockIdx.x, j = threadIdx.x, b = bt >> 6;
  hr[j] = Hh[bt*256 + j];
  __syncthreads();
  float a = 0.f;
  #pragma unroll 4
  for (int k = 0; k < 256; ++k) a += hr[k] * kW[k*256 + j];
  a += kb[j];
  float p = a * q[b*256 + j];
  #pragma unroll
  for (int o = 1; o < 64; o <<= 1) p += __shfl_xor(p, o);
  if ((j & 63) == 0) pw[j >> 6] = p;
  __syncthreads();
  float s = (pw[0] + pw[1] + pw[2] + pw[3]) * (1.f/16.f);
  float sig = 1.f / (1.f + __expf(-s));
  out[bt*256 + j] = hr[j] * sig;
}

// ---------------------------------------------------------------------------
extern "C" void kernel_launch(void* const* d_in, const int* in_sizes, int n_in,
                              void* d_out, int out_size, void* d_ws, size_t ws_size,
                              hipStream_t stream){
  (void)in_sizes; (void)n_in; (void)out_size; (void)ws_size;
  const float* x    = (const float*)d_in[0];
  const float* e_s  = (const float*)d_in[1];
  const float* qW   = (const float*)d_in[2];
  const float* qb   = (const float*)d_in[3];
  const float* kW   = (const float*)d_in[4];
  const float* kb   = (const float*)d_in[5];
  const float* m1W  = (const float*)d_in[6];
  const float* m1b  = (const float*)d_in[7];
  const float* m1g  = (const float*)d_in[8];
  const float* m1be = (const float*)d_in[9];
  const float* m2W  = (const float*)d_in[10];
  const float* m2b  = (const float*)d_in[11];
  const float* m2g  = (const float*)d_in[12];
  const float* m2be = (const float*)d_in[13];
  const float* p1W  = (const float*)d_in[14];
  const float* p1b  = (const float*)d_in[15];
  const float* p1g  = (const float*)d_in[16];
  const float* p1be = (const float*)d_in[17];
  const float* p2W  = (const float*)d_in[18];
  const float* p2b  = (const float*)d_in[19];
  const float* p2g  = (const float*)d_in[20];
  const float* p2be = (const float*)d_in[21];

  char* ws = (char*)d_ws;
  unsigned short* WT = (unsigned short*)ws; ws += 33554432;
  unsigned short* fc = (unsigned short*)ws; ws += 67108864;
  float* P  = (float*)ws; ws += 33554432;
  float* a1 = (float*)ws; ws += 524288;
  float* h1 = (float*)ws; ws += 524288;
  float* a2 = (float*)ws; ws += 524288;
  float* h2 = (float*)ws; ws += 524288;
  float* a3 = (float*)ws; ws += 524288;
  float* h3 = (float*)ws; ws += 524288;
  float* a4 = (float*)ws; ws += 524288;
  float* Hh = (float*)ws; ws += 524288;
  float* qv = (float*)ws; ws += 8192;
  float* out = (float*)d_out;

  k_wt    <<<dim3(1024, 4), 256, 0, stream>>>(m1W, WT);
  k_corr  <<<512, 256, 0, stream>>>(x, fc);
  k_gemm  <<<dim3(64, 4, 2), 256, 0, stream>>>(fc, WT, P);
  k_reduce<<<512, 256, 0, stream>>>(P, m1b, a1);
  k_bn    <<<256, 256, 0, stream>>>(a1, m1g, m1be, h1);
  k_sg<256,false><<<256, 256, 0, stream>>>(h1, nullptr, m2W, m2b, a2);
  k_bn    <<<256, 256, 0, stream>>>(a2, m2g, m2be, h2);
  k_sg<512,true> <<<256, 256, 0, stream>>>(h2, e_s, p1W, p1b, a3);
  k_bn    <<<256, 256, 0, stream>>>(a3, p1g, p1be, h3);
  k_sg<256,false><<<256, 256, 0, stream>>>(h3, nullptr, p2W, p2b, a4);
  k_bn    <<<256, 256, 0, stream>>>(a4, p2g, p2be, Hh);
  k_qmean <<<8, 256, 0, stream>>>(Hh, qW, qb, qv);
  k_att   <<<512, 256, 0, stream>>>(Hh, kW, kb, qv, out);
}

// Round 3
// 149.525 us; speedup vs baseline: 1.3594x; 1.3594x over previous
//
#include <hip/hip_runtime.h>
#include <stdint.h>
#include <stddef.h>

// ---------------------------------------------------------------------------
// ModuleGARO: corr(256x256 per bt, 512 bt) -> [512,65536]@[65536,256] GEMM ->
// BN/ReLU chain -> sigmoid QK attention scale.
// ws layout (bytes):
//   WT   bf16 256x65536   33,554,432
//   fc   bf16 512x65536   67,108,864
//   P    f32  64x512x256  33,554,432
//   a1,h1,a2,h2,a3,h3,a4,Hh  f32 512x256 each  8x524,288
//   q    f32  8x256       8,192
// total ~132 MB
// ---------------------------------------------------------------------------

typedef short short8 __attribute__((ext_vector_type(8)));
typedef float f32x4 __attribute__((ext_vector_type(4)));

#define DEV __device__ __forceinline__

DEV unsigned short f2bf(float f){
  union { float f; unsigned u; } v; v.f = f;
  unsigned r = v.u + 0x7FFFu + ((v.u >> 16) & 1u);   // RNE
  return (unsigned short)(r >> 16);
}
DEV float bf2f(unsigned short b){
  union { unsigned u; float f; } v; v.u = ((unsigned)b) << 16;
  return v.f;
}
DEV void gload_lds16(const void* g, void* l){
  __builtin_amdgcn_global_load_lds(
      (const __attribute__((address_space(1))) unsigned int*)g,
      (__attribute__((address_space(3))) unsigned int*)l, 16, 0, 0);
}

// ---------------------------------------------------------------------------
// k_wt: WT[o][k] = bf16(m1W[k][o]); 64x64 tiles via LDS transpose.
// ---------------------------------------------------------------------------
__global__ __launch_bounds__(256) void k_wt(const float* __restrict__ W,
                                            unsigned short* __restrict__ WT){
  __shared__ float tile[64][65];
  const int k0 = blockIdx.x * 64;
  const int o0 = blockIdx.y * 64;
  const int tr = threadIdx.x >> 6;   // 0..3
  const int tc = threadIdx.x & 63;
  #pragma unroll
  for (int i = 0; i < 16; ++i){
    int kr = i*4 + tr;
    tile[kr][tc] = W[(size_t)(k0+kr)*256 + o0 + tc];
  }
  __syncthreads();
  #pragma unroll
  for (int i = 0; i < 16; ++i){
    int orow = i*4 + tr;
    WT[(size_t)(o0+orow)*65536 + k0 + tc] = f2bf(tile[tc][orow]);
  }
}

// ---------------------------------------------------------------------------
// k_corr: one block per bt. corr = (y^T y) * rs_i * rs_j, clip [-1,1], bf16.
// ---------------------------------------------------------------------------
__global__ __launch_bounds__(256) void k_corr(const float* __restrict__ x,
                                              unsigned short* __restrict__ fc){
  __shared__ unsigned short yT[256*72];
  __shared__ float rs[256];
  __shared__ unsigned short stg[4][64*40];
  const int bt = blockIdx.x;
  const float* xb = x + (size_t)bt * 16384;   // 64 samples x 256 vars
  const int i = threadIdx.x;                  // column (variable) index

  float sum = 0.f;
  #pragma unroll 8
  for (int s = 0; s < 64; ++s) sum += xb[s*256 + i];
  const float mean = sum * (1.f/64.f);

  float ss = 0.f;
  unsigned int* yT32 = (unsigned int*)yT;
  #pragma unroll 4
  for (int s = 0; s < 64; s += 2){
    float v0 = xb[s*256 + i] - mean;
    float v1 = xb[(s+1)*256 + i] - mean;
    unsigned short b0 = f2bf(v0), b1 = f2bf(v1);
    float r0 = bf2f(b0), r1 = bf2f(b1);
    ss += r0*r0 + r1*r1;                      // sumsq of the *rounded* values
    yT32[(i*72 + s) >> 1] = (unsigned)b0 | ((unsigned)b1 << 16);
  }
  rs[i] = rsqrtf(ss);
  __syncthreads();

  const int w   = threadIdx.x >> 6;           // wave 0..3 -> rows w*64..w*64+63
  const int l   = threadIdx.x & 63;
  const int l15 = l & 15, lg = l >> 4;

  short8 RF[4][2];
  #pragma unroll
  for (int rt = 0; rt < 4; ++rt){
    int row = w*64 + rt*16 + l15;
    #pragma unroll
    for (int ks = 0; ks < 2; ++ks)
      RF[rt][ks] = *(const short8*)&yT[row*72 + ks*32 + lg*8];
  }
  float rrow[4][4];
  #pragma unroll
  for (int rt = 0; rt < 4; ++rt)
    #pragma unroll
    for (int r = 0; r < 4; ++r)
      rrow[rt][r] = rs[w*64 + rt*16 + lg*4 + r];

  unsigned short* sg = stg[w];
  for (int cc = 0; cc < 8; ++cc){             // 8 chunks of 32 output cols
    short8 CF[2][2];
    #pragma unroll
    for (int ct = 0; ct < 2; ++ct){
      int col = cc*32 + ct*16 + l15;
      #pragma unroll
      for (int ks = 0; ks < 2; ++ks)
        CF[ct][ks] = *(const short8*)&yT[col*72 + ks*32 + lg*8];
    }
    f32x4 acc[4][2];
    #pragma unroll
    for (int rt = 0; rt < 4; ++rt)
      #pragma unroll
      for (int ct = 0; ct < 2; ++ct)
        acc[rt][ct] = (f32x4){0.f,0.f,0.f,0.f};
    #pragma unroll
    for (int ks = 0; ks < 2; ++ks)
      #pragma unroll
      for (int rt = 0; rt < 4; ++rt)
        #pragma unroll
        for (int ct = 0; ct < 2; ++ct)
          acc[rt][ct] = __builtin_amdgcn_mfma_f32_16x16x32_bf16(
              RF[rt][ks], CF[ct][ks], acc[rt][ct], 0, 0, 0);

    float rc[2] = { rs[cc*32 + l15], rs[cc*32 + 16 + l15] };
    #pragma unroll
    for (int rt = 0; rt < 4; ++rt)
      #pragma unroll
      for (int ct = 0; ct < 2; ++ct)
        #pragma unroll
        for (int r = 0; r < 4; ++r){
          float v = acc[rt][ct][r] * rrow[rt][r] * rc[ct];
          v = fminf(fmaxf(v, -1.f), 1.f);
          sg[(rt*16 + lg*4 + r)*40 + ct*16 + l15] = f2bf(v);
        }
    #pragma unroll
    for (int idx = 0; idx < 4; ++idx){
      int c = idx*64 + l;
      int rowL = c >> 2, ch = c & 3;
      short8 v = *(const short8*)&sg[rowL*40 + ch*8];
      *(short8*)&fc[(size_t)bt*65536 + (size_t)(w*64 + rowL)*256 + cc*32 + ch*8] = v;
    }
  }
}

// ---------------------------------------------------------------------------
// k_gemm: [512,65536]bf16 @ WT^T -> split-K fp32 partials.
// ---------------------------------------------------------------------------
__global__ __launch_bounds__(256) void k_gemm(const unsigned short* __restrict__ fc,
                                              const unsigned short* __restrict__ WT,
                                              float* __restrict__ P){
  __shared__ unsigned short Al[128*64];
  __shared__ unsigned short Bl[128*64];
  const int ksb = blockIdx.x;
  const int m0  = blockIdx.y * 128;
  const int n0  = blockIdx.z * 128;
  const int k0  = ksb * 1024;
  const int t   = threadIdx.x;
  const int w = t >> 6, l = t & 63, l15 = l & 15, lg = l >> 4;
  const int wrow = (w >> 1) * 64, wcol = (w & 1) * 64;

  f32x4 acc[4][4];
  #pragma unroll
  for (int a = 0; a < 4; ++a)
    #pragma unroll
    for (int b = 0; b < 4; ++b) acc[a][b] = (f32x4){0.f,0.f,0.f,0.f};

  for (int kt = 0; kt < 16; ++kt){
    const int kk = k0 + kt*64;
    #pragma unroll
    for (int i2 = 0; i2 < 4; ++i2){
      int c = i2*256 + t;
      int row = c >> 3, ch = c & 7;
      int sch = ch ^ (row & 7);
      gload_lds16(fc + (size_t)(m0+row)*65536 + kk + sch*8, &Al[c*8]);
    }
    #pragma unroll
    for (int i2 = 0; i2 < 4; ++i2){
      int c = i2*256 + t;
      int row = c >> 3, ch = c & 7;
      int sch = ch ^ (row & 7);
      gload_lds16(WT + (size_t)(n0+row)*65536 + kk + sch*8, &Bl[c*8]);
    }
    __syncthreads();
    #pragma unroll
    for (int ks = 0; ks < 2; ++ks){
      short8 af[4], bf[4];
      #pragma unroll
      for (int rt = 0; rt < 4; ++rt){
        int row = wrow + rt*16 + l15;
        int pch = (ks*4 + lg) ^ (row & 7);
        af[rt] = *(const short8*)&Al[row*64 + pch*8];
      }
      #pragma unroll
      for (int ct = 0; ct < 4; ++ct){
        int row = wcol + ct*16 + l15;
        int pch = (ks*4 + lg) ^ (row & 7);
        bf[ct] = *(const short8*)&Bl[row*64 + pch*8];
      }
      #pragma unroll
      for (int rt = 0; rt < 4; ++rt)
        #pragma unroll
        for (int ct = 0; ct < 4; ++ct)
          acc[rt][ct] = __builtin_amdgcn_mfma_f32_16x16x32_bf16(
              af[rt], bf[ct], acc[rt][ct], 0, 0, 0);
    }
    __syncthreads();
  }

  float* Pb = P + (size_t)ksb * 131072;
  #pragma unroll
  for (int rt = 0; rt < 4; ++rt)
    #pragma unroll
    for (int ct = 0; ct < 4; ++ct)
      #pragma unroll
      for (int r = 0; r < 4; ++r){
        int row = m0 + wrow + rt*16 + lg*4 + r;
        int col = n0 + wcol + ct*16 + l15;
        Pb[(size_t)row*256 + col] = acc[rt][ct][r];
      }
}

// ---------------------------------------------------------------------------
// k_reduce: a[bt][j] = sum_ks P[ks][bt][j] + bias[j]
// ---------------------------------------------------------------------------
__global__ __launch_bounds__(256) void k_reduce(const float* __restrict__ P,
                                                const float* __restrict__ bias,
                                                float* __restrict__ a){
  const int bt = blockIdx.x, j = threadIdx.x;
  float s = 0.f;
  #pragma unroll 8
  for (int ks = 0; ks < 64; ++ks) s += P[(size_t)ks*131072 + bt*256 + j];
  a[bt*256 + j] = s + bias[j];
}

// ---------------------------------------------------------------------------
// k_bn: per-column batch stats over 512 rows (biased var), apply + ReLU.
// ---------------------------------------------------------------------------
__global__ __launch_bounds__(256) void k_bn(const float* __restrict__ a,
                                            const float* __restrict__ g,
                                            const float* __restrict__ beta,
                                            float* __restrict__ h){
  const int j = blockIdx.x, t = threadIdx.x;
  float v0 = a[t*256 + j], v1 = a[(t+256)*256 + j];
  float s = v0 + v1, q = v0*v0 + v1*v1;
  #pragma unroll
  for (int o = 1; o < 64; o <<= 1){ s += __shfl_xor(s, o); q += __shfl_xor(q, o); }
  __shared__ float sw[4], qw[4];
  if ((t & 63) == 0){ sw[t >> 6] = s; qw[t >> 6] = q; }
  __syncthreads();
  float S = sw[0] + sw[1] + sw[2] + sw[3];
  float Q = qw[0] + qw[1] + qw[2] + qw[3];
  float mu  = S * (1.f/512.f);
  float var = Q * (1.f/512.f) - mu*mu;
  float sc = g[j] * rsqrtf(var + 1e-5f);
  float sh = beta[j] - mu * sc;
  h[t*256 + j]       = fmaxf(v0*sc + sh, 0.f);
  h[(t+256)*256 + j] = fmaxf(v1*sc + sh, 0.f);
}

// ---------------------------------------------------------------------------
// k_sg: small GEMM a = [x | es?] @ W + bias, W staged in LDS (64-row chunks
// via global_load_lds w16). Block = 2 bt rows; thread = output col.
// ---------------------------------------------------------------------------
template<int KK, bool CAT>
__global__ __launch_bounds__(256) void k_sg(const float* __restrict__ xin,
                                            const float* __restrict__ es,
                                            const float* __restrict__ W,
                                            const float* __restrict__ bias,
                                            float* __restrict__ aout){
  __shared__ float Wl[64*256];   // 64 KB: one K-chunk of W
  __shared__ float xr[2][KK];
  const int bt0 = blockIdx.x * 2;
  const int t = threadIdx.x;
  xr[0][t] = xin[bt0*256 + t];
  xr[1][t] = xin[(bt0+1)*256 + t];
  if constexpr (CAT){
    float e = es[(bt0 >> 6)*256 + t];
    xr[0][256 + t] = e;
    xr[1][256 + t] = e;
  }
  float a0 = 0.f, a1 = 0.f;
  for (int k0 = 0; k0 < KK; k0 += 64){
    __syncthreads();                       // prev chunk consumed (also xr ready)
    const float* Wg = W + (size_t)k0 * 256;
    #pragma unroll
    for (int i = 0; i < 16; ++i){
      int c = i*256 + t;                   // float4 index, linear in t per wave
      gload_lds16(Wg + c*4, &Wl[c*4]);
    }
    __syncthreads();                       // drains vmcnt (gload_lds complete)
    #pragma unroll 16
    for (int k = 0; k < 64; ++k){
      float wv = Wl[k*256 + t];            // lane-contiguous: conflict-free
      a0 += xr[0][k0+k] * wv;              // broadcast: conflict-free
      a1 += xr[1][k0+k] * wv;
    }
  }
  aout[bt0*256 + t]     = a0 + bias[t];
  aout[(bt0+1)*256 + t] = a1 + bias[t];
}

// ---------------------------------------------------------------------------
// k_qmean: per b: Hm = mean_t Hh[b,t,:]; q = Hm @ qW + qb (qW staged in LDS)
// ---------------------------------------------------------------------------
__global__ __launch_bounds__(256) void k_qmean(const float* __restrict__ Hh,
                                               const float* __restrict__ qW,
                                               const float* __restrict__ qb,
                                               float* __restrict__ q){
  __shared__ float Wl[64*256];
  __shared__ float hm[256];
  const int b = blockIdx.x, t = threadIdx.x;
  float s = 0.f;
  #pragma unroll 8
  for (int tt = 0; tt < 64; ++tt) s += Hh[((b<<6)+tt)*256 + t];
  hm[t] = s * (1.f/64.f);
  float a = 0.f;
  for (int k0 = 0; k0 < 256; k0 += 64){
    __syncthreads();
    const float* Wg = qW + (size_t)k0 * 256;
    #pragma unroll
    for (int i = 0; i < 16; ++i){
      int c = i*256 + t;
      gload_lds16(Wg + c*4, &Wl[c*4]);
    }
    __syncthreads();
    #pragma unroll 16
    for (int k = 0; k < 64; ++k)
      a += hm[k0+k] * Wl[k*256 + t];
  }
  q[b*256 + t] = a + qb[t];
}

// ---------------------------------------------------------------------------
// k_att: per 2 bt rows: kvec = Hh_row @ kW + kb; s = dot(q_b,kvec)/16;
//        out = Hh_row * sigmoid(s). kW staged in LDS.
// NOTE: grid must be 256 blocks (2 rows per block) — 512 was the R2 OOB bug.
// ---------------------------------------------------------------------------
__global__ __launch_bounds__(256) void k_att(const float* __restrict__ Hh,
                                             const float* __restrict__ kW,
                                             const float* __restrict__ kb,
                                             const float* __restrict__ q,
                                             float* __restrict__ out){
  __shared__ float Wl[64*256];
  __shared__ float xr[2][256];
  __shared__ float pw[2][4];
  const int bt0 = blockIdx.x * 2;
  const int b = bt0 >> 6;
  const int t = threadIdx.x;
  xr[0][t] = Hh[bt0*256 + t];
  xr[1][t] = Hh[(bt0+1)*256 + t];
  float a0 = 0.f, a1 = 0.f;
  for (int k0 = 0; k0 < 256; k0 += 64){
    __syncthreads();
    const float* Wg = kW + (size_t)k0 * 256;
    #pragma unroll
    for (int i = 0; i < 16; ++i){
      int c = i*256 + t;
      gload_lds16(Wg + c*4, &Wl[c*4]);
    }
    __syncthreads();
    #pragma unroll 16
    for (int k = 0; k < 64; ++k){
      float wv = Wl[k*256 + t];
      a0 += xr[0][k0+k] * wv;
      a1 += xr[1][k0+k] * wv;
    }
  }
  float qv = q[b*256 + t];
  float p0 = (a0 + kb[t]) * qv;
  float p1 = (a1 + kb[t]) * qv;
  #pragma unroll
  for (int o = 1; o < 64; o <<= 1){
    p0 += __shfl_xor(p0, o);
    p1 += __shfl_xor(p1, o);
  }
  if ((t & 63) == 0){ pw[0][t >> 6] = p0; pw[1][t >> 6] = p1; }
  __syncthreads();
  float s0 = (pw[0][0] + pw[0][1] + pw[0][2] + pw[0][3]) * (1.f/16.f);
  float s1 = (pw[1][0] + pw[1][1] + pw[1][2] + pw[1][3]) * (1.f/16.f);
  float g0 = 1.f / (1.f + __expf(-s0));
  float g1 = 1.f / (1.f + __expf(-s1));
  out[bt0*256 + t]     = xr[0][t] * g0;
  out[(bt0+1)*256 + t] = xr[1][t] * g1;
}

// ---------------------------------------------------------------------------
extern "C" void kernel_launch(void* const* d_in, const int* in_sizes, int n_in,
                              void* d_out, int out_size, void* d_ws, size_t ws_size,
                              hipStream_t stream){
  (void)in_sizes; (void)n_in; (void)out_size; (void)ws_size;
  const float* x    = (const float*)d_in[0];
  const float* e_s  = (const float*)d_in[1];
  const float* qW   = (const float*)d_in[2];
  const float* qb   = (const float*)d_in[3];
  const float* kW   = (const float*)d_in[4];
  const float* kb   = (const float*)d_in[5];
  const float* m1W  = (const float*)d_in[6];
  const float* m1b  = (const float*)d_in[7];
  const float* m1g  = (const float*)d_in[8];
  const float* m1be = (const float*)d_in[9];
  const float* m2W  = (const float*)d_in[10];
  const float* m2b  = (const float*)d_in[11];
  const float* m2g  = (const float*)d_in[12];
  const float* m2be = (const float*)d_in[13];
  const float* p1W  = (const float*)d_in[14];
  const float* p1b  = (const float*)d_in[15];
  const float* p1g  = (const float*)d_in[16];
  const float* p1be = (const float*)d_in[17];
  const float* p2W  = (const float*)d_in[18];
  const float* p2b  = (const float*)d_in[19];
  const float* p2g  = (const float*)d_in[20];
  const float* p2be = (const float*)d_in[21];

  char* ws = (char*)d_ws;
  unsigned short* WT = (unsigned short*)ws; ws += 33554432;
  unsigned short* fc = (unsigned short*)ws; ws += 67108864;
  float* P  = (float*)ws; ws += 33554432;
  float* a1 = (float*)ws; ws += 524288;
  float* h1 = (float*)ws; ws += 524288;
  float* a2 = (float*)ws; ws += 524288;
  float* h2 = (float*)ws; ws += 524288;
  float* a3 = (float*)ws; ws += 524288;
  float* h3 = (float*)ws; ws += 524288;
  float* a4 = (float*)ws; ws += 524288;
  float* Hh = (float*)ws; ws += 524288;
  float* qv = (float*)ws; ws += 8192;
  float* out = (float*)d_out;

  k_wt    <<<dim3(1024, 4), 256, 0, stream>>>(m1W, WT);
  k_corr  <<<512, 256, 0, stream>>>(x, fc);
  k_gemm  <<<dim3(64, 4, 2), 256, 0, stream>>>(fc, WT, P);
  k_reduce<<<512, 256, 0, stream>>>(P, m1b, a1);
  k_bn    <<<256, 256, 0, stream>>>(a1, m1g, m1be, h1);
  k_sg<256,false><<<256, 256, 0, stream>>>(h1, nullptr, m2W, m2b, a2);
  k_bn    <<<256, 256, 0, stream>>>(a2, m2g, m2be, h2);
  k_sg<512,true> <<<256, 256, 0, stream>>>(h2, e_s, p1W, p1b, a3);
  k_bn    <<<256, 256, 0, stream>>>(a3, p1g, p1be, h3);
  k_sg<256,false><<<256, 256, 0, stream>>>(h3, nullptr, p2W, p2b, a4);
  k_bn    <<<256, 256, 0, stream>>>(a4, p2g, p2be, Hh);
  k_qmean <<<8, 256, 0, stream>>>(Hh, qW, qb, qv);
  k_att   <<<256, 256, 0, stream>>>(Hh, kW, kb, qv, out);   // 2 rows/block
}

// Round 4
// 147.163 us; speedup vs baseline: 1.3812x; 1.0161x over previous
//
#include <hip/hip_runtime.h>
#include <stdint.h>
#include <stddef.h>

// ---------------------------------------------------------------------------
// ModuleGARO: corr(256x256 per bt, 512 bt) -> [512,65536]@[65536,256] GEMM ->
// BN/ReLU chain -> sigmoid QK attention scale.
// BN note: Linear bias cancels exactly in BatchNorm (x - mu), so all GEMM
// biases (m1b,m2b,p1b,p2b) are dropped; BN is {scale,shift} per column
// computed by k_stats and applied inline (with ReLU) at each consumer load.
// ws layout (bytes):
//   WT   bf16 256x65536   33,554,432
//   fc   bf16 512x65536   67,108,864
//   P    f32  64x512x256  33,554,432
//   z1..z4  f32 512x256   4 x 524,288
//   ss1..ss4 float2[256]  4 x 2,048
//   q    f32  8x256       8,192
// ---------------------------------------------------------------------------

typedef short short8 __attribute__((ext_vector_type(8)));
typedef float f32x4 __attribute__((ext_vector_type(4)));

#define DEV __device__ __forceinline__

DEV unsigned short f2bf(float f){
  union { float f; unsigned u; } v; v.f = f;
  unsigned r = v.u + 0x7FFFu + ((v.u >> 16) & 1u);   // RNE
  return (unsigned short)(r >> 16);
}
DEV float bf2f(unsigned short b){
  union { unsigned u; float f; } v; v.u = ((unsigned)b) << 16;
  return v.f;
}
DEV void gload_lds16(const void* g, void* l){
  __builtin_amdgcn_global_load_lds(
      (const __attribute__((address_space(1))) unsigned int*)g,
      (__attribute__((address_space(3))) unsigned int*)l, 16, 0, 0);
}

// ---------------------------------------------------------------------------
// k_wt: WT[o][k] = bf16(m1W[k][o]); 64x64 tiles via LDS transpose.
// ---------------------------------------------------------------------------
__global__ __launch_bounds__(256) void k_wt(const float* __restrict__ W,
                                            unsigned short* __restrict__ WT){
  __shared__ float tile[64][65];
  const int k0 = blockIdx.x * 64;
  const int o0 = blockIdx.y * 64;
  const int tr = threadIdx.x >> 6;   // 0..3
  const int tc = threadIdx.x & 63;
  #pragma unroll
  for (int i = 0; i < 16; ++i){
    int kr = i*4 + tr;
    tile[kr][tc] = W[(size_t)(k0+kr)*256 + o0 + tc];
  }
  __syncthreads();
  #pragma unroll
  for (int i = 0; i < 16; ++i){
    int orow = i*4 + tr;
    WT[(size_t)(o0+orow)*65536 + k0 + tc] = f2bf(tile[tc][orow]);
  }
}

// ---------------------------------------------------------------------------
// k_corr: one block per bt. corr = (y^T y) * rs_i * rs_j, clip [-1,1], bf16.
// ---------------------------------------------------------------------------
__global__ __launch_bounds__(256) void k_corr(const float* __restrict__ x,
                                              unsigned short* __restrict__ fc){
  __shared__ unsigned short yT[256*72];
  __shared__ float rs[256];
  __shared__ unsigned short stg[4][64*40];
  const int bt = blockIdx.x;
  const float* xb = x + (size_t)bt * 16384;   // 64 samples x 256 vars
  const int i = threadIdx.x;                  // column (variable) index

  float sum = 0.f;
  #pragma unroll 8
  for (int s = 0; s < 64; ++s) sum += xb[s*256 + i];
  const float mean = sum * (1.f/64.f);

  float ss = 0.f;
  unsigned int* yT32 = (unsigned int*)yT;
  #pragma unroll 4
  for (int s = 0; s < 64; s += 2){
    float v0 = xb[s*256 + i] - mean;
    float v1 = xb[(s+1)*256 + i] - mean;
    unsigned short b0 = f2bf(v0), b1 = f2bf(v1);
    float r0 = bf2f(b0), r1 = bf2f(b1);
    ss += r0*r0 + r1*r1;                      // sumsq of the *rounded* values
    yT32[(i*72 + s) >> 1] = (unsigned)b0 | ((unsigned)b1 << 16);
  }
  rs[i] = rsqrtf(ss);
  __syncthreads();

  const int w   = threadIdx.x >> 6;           // wave 0..3 -> rows w*64..w*64+63
  const int l   = threadIdx.x & 63;
  const int l15 = l & 15, lg = l >> 4;

  short8 RF[4][2];
  #pragma unroll
  for (int rt = 0; rt < 4; ++rt){
    int row = w*64 + rt*16 + l15;
    #pragma unroll
    for (int ks = 0; ks < 2; ++ks)
      RF[rt][ks] = *(const short8*)&yT[row*72 + ks*32 + lg*8];
  }
  float rrow[4][4];
  #pragma unroll
  for (int rt = 0; rt < 4; ++rt)
    #pragma unroll
    for (int r = 0; r < 4; ++r)
      rrow[rt][r] = rs[w*64 + rt*16 + lg*4 + r];

  unsigned short* sg = stg[w];
  for (int cc = 0; cc < 8; ++cc){             // 8 chunks of 32 output cols
    short8 CF[2][2];
    #pragma unroll
    for (int ct = 0; ct < 2; ++ct){
      int col = cc*32 + ct*16 + l15;
      #pragma unroll
      for (int ks = 0; ks < 2; ++ks)
        CF[ct][ks] = *(const short8*)&yT[col*72 + ks*32 + lg*8];
    }
    f32x4 acc[4][2];
    #pragma unroll
    for (int rt = 0; rt < 4; ++rt)
      #pragma unroll
      for (int ct = 0; ct < 2; ++ct)
        acc[rt][ct] = (f32x4){0.f,0.f,0.f,0.f};
    #pragma unroll
    for (int ks = 0; ks < 2; ++ks)
      #pragma unroll
      for (int rt = 0; rt < 4; ++rt)
        #pragma unroll
        for (int ct = 0; ct < 2; ++ct)
          acc[rt][ct] = __builtin_amdgcn_mfma_f32_16x16x32_bf16(
              RF[rt][ks], CF[ct][ks], acc[rt][ct], 0, 0, 0);

    float rc[2] = { rs[cc*32 + l15], rs[cc*32 + 16 + l15] };
    #pragma unroll
    for (int rt = 0; rt < 4; ++rt)
      #pragma unroll
      for (int ct = 0; ct < 2; ++ct)
        #pragma unroll
        for (int r = 0; r < 4; ++r){
          float v = acc[rt][ct][r] * rrow[rt][r] * rc[ct];
          v = fminf(fmaxf(v, -1.f), 1.f);
          sg[(rt*16 + lg*4 + r)*40 + ct*16 + l15] = f2bf(v);
        }
    #pragma unroll
    for (int idx = 0; idx < 4; ++idx){
      int c = idx*64 + l;
      int rowL = c >> 2, ch = c & 3;
      short8 v = *(const short8*)&sg[rowL*40 + ch*8];
      *(short8*)&fc[(size_t)bt*65536 + (size_t)(w*64 + rowL)*256 + cc*32 + ch*8] = v;
    }
  }
}

// ---------------------------------------------------------------------------
// k_gemm: [512,65536]bf16 @ WT^T -> split-K fp32 partials (no bias).
// BM=128, BN=256 (N untiled: fc read once), BK=64, 512 thr / 8 waves
// (wave tile 64x64), 2-phase double-buffered LDS: stage(kt+1) issued before
// compute(kt), single barrier per tile. grid (64 ksplit, 4 Mtiles).
// ---------------------------------------------------------------------------
__global__ __launch_bounds__(512) void k_gemm(const unsigned short* __restrict__ fc,
                                              const unsigned short* __restrict__ WT,
                                              float* __restrict__ P){
  __shared__ unsigned short Al[2][128*64];
  __shared__ unsigned short Bl[2][256*64];
  const int ksb = blockIdx.x;
  const int m0  = blockIdx.y * 128;
  const int k0  = ksb * 1024;
  const int t   = threadIdx.x;
  const int w = t >> 6, l = t & 63, l15 = l & 15, lg = l >> 4;
  const int wr = (w >> 2) * 64;     // 0,64
  const int wc = (w & 3) * 64;      // 0..192

  auto stage = [&](int b, int kt){
    const int kk = k0 + kt*64;
    #pragma unroll
    for (int i = 0; i < 2; ++i){
      int c = i*512 + t;
      int row = c >> 3, ch = c & 7;
      int sch = ch ^ (row & 7);
      gload_lds16(fc + (size_t)(m0+row)*65536 + kk + sch*8, &Al[b][c*8]);
    }
    #pragma unroll
    for (int i = 0; i < 4; ++i){
      int c = i*512 + t;
      int row = c >> 3, ch = c & 7;
      int sch = ch ^ (row & 7);
      gload_lds16(WT + (size_t)row*65536 + kk + sch*8, &Bl[b][c*8]);
    }
  };

  f32x4 acc[4][4];
  #pragma unroll
  for (int a = 0; a < 4; ++a)
    #pragma unroll
    for (int b = 0; b < 4; ++b) acc[a][b] = (f32x4){0.f,0.f,0.f,0.f};

  stage(0, 0);
  int cur = 0;
  for (int kt = 0; kt < 16; ++kt){
    __syncthreads();                 // buf[cur] staged; prev buf reads done
    if (kt < 15) stage(cur ^ 1, kt + 1);
    #pragma unroll
    for (int ks = 0; ks < 2; ++ks){
      short8 af[4], bf[4];
      #pragma unroll
      for (int rt = 0; rt < 4; ++rt){
        int row = wr + rt*16 + l15;
        int pch = (ks*4 + lg) ^ (row & 7);
        af[rt] = *(const short8*)&Al[cur][row*64 + pch*8];
      }
      #pragma unroll
      for (int ct = 0; ct < 4; ++ct){
        int row = wc + ct*16 + l15;
        int pch = (ks*4 + lg) ^ (row & 7);
        bf[ct] = *(const short8*)&Bl[cur][row*64 + pch*8];
      }
      #pragma unroll
      for (int rt = 0; rt < 4; ++rt)
        #pragma unroll
        for (int ct = 0; ct < 4; ++ct)
          acc[rt][ct] = __builtin_amdgcn_mfma_f32_16x16x32_bf16(
              af[rt], bf[ct], acc[rt][ct], 0, 0, 0);
    }
    cur ^= 1;
  }

  float* Pb = P + (size_t)ksb * 131072;
  #pragma unroll
  for (int rt = 0; rt < 4; ++rt)
    #pragma unroll
    for (int ct = 0; ct < 4; ++ct)
      #pragma unroll
      for (int r = 0; r < 4; ++r){
        int row = m0 + wr + rt*16 + lg*4 + r;
        int col = wc + ct*16 + l15;
        Pb[(size_t)row*256 + col] = acc[rt][ct][r];
      }
}

// ---------------------------------------------------------------------------
// k_reduce: z[bt][j] = sum_ks P[ks][bt][j]  (float4, no bias)
// grid 128 blocks x 256 thr: 4 rows/block, 64 float4-cols.
// ---------------------------------------------------------------------------
__global__ __launch_bounds__(256) void k_reduce(const float* __restrict__ P,
                                                float* __restrict__ z){
  const int row = blockIdx.x*4 + (threadIdx.x >> 6);
  const int j4  = (threadIdx.x & 63) * 4;
  f32x4 s = (f32x4){0.f,0.f,0.f,0.f};
  #pragma unroll 8
  for (int ks = 0; ks < 64; ++ks)
    s += *(const f32x4*)&P[(size_t)ks*131072 + row*256 + j4];
  *(f32x4*)&z[row*256 + j4] = s;
}

// ---------------------------------------------------------------------------
// k_stats: per-column batch stats over 512 rows (biased var) ->
// ss[j] = {sc, sh} with sc = g*rsqrt(var+eps), sh = beta - mu*sc.
// ---------------------------------------------------------------------------
__global__ __launch_bounds__(256) void k_stats(const float* __restrict__ z,
                                               const float* __restrict__ g,
                                               const float* __restrict__ beta,
                                               float2* __restrict__ ss){
  const int j = blockIdx.x, t = threadIdx.x;
  float v0 = z[t*256 + j], v1 = z[(t+256)*256 + j];
  float s = v0 + v1, q = v0*v0 + v1*v1;
  #pragma unroll
  for (int o = 1; o < 64; o <<= 1){ s += __shfl_xor(s, o); q += __shfl_xor(q, o); }
  __shared__ float sw[4], qw[4];
  if ((t & 63) == 0){ sw[t >> 6] = s; qw[t >> 6] = q; }
  __syncthreads();
  if (t == 0){
    float S = sw[0] + sw[1] + sw[2] + sw[3];
    float Q = qw[0] + qw[1] + qw[2] + qw[3];
    float mu  = S * (1.f/512.f);
    float var = Q * (1.f/512.f) - mu*mu;
    float sc = g[j] * rsqrtf(var + 1e-5f);
    ss[j] = make_float2(sc, beta[j] - mu*sc);
  }
}

// ---------------------------------------------------------------------------
// k_sg: z_out = [relu(bn(z_in)) | es?] @ W  (no bias; BN applied inline).
// W staged in double-buffered LDS chunks. Block = 2 bt rows; thread = col.
// ---------------------------------------------------------------------------
template<int KK, bool CAT>
__global__ __launch_bounds__(256) void k_sg(const float* __restrict__ zin,
                                            const float2* __restrict__ ss,
                                            const float* __restrict__ es,
                                            const float* __restrict__ W,
                                            float* __restrict__ zout){
  __shared__ float Wl[2][64*256];   // 128 KB double-buffered K-chunks
  __shared__ float xr[2][KK];
  const int bt0 = blockIdx.x * 2;
  const int t = threadIdx.x;
  float2 sv = ss[t];
  xr[0][t] = fmaxf(zin[bt0*256 + t]*sv.x + sv.y, 0.f);
  xr[1][t] = fmaxf(zin[(bt0+1)*256 + t]*sv.x + sv.y, 0.f);
  if constexpr (CAT){
    float e = es[(bt0 >> 6)*256 + t];
    xr[0][256 + t] = e;
    xr[1][256 + t] = e;
  }
  auto stage = [&](int b, int c0){
    const float* Wg = W + (size_t)c0 * 64 * 256;
    #pragma unroll
    for (int i = 0; i < 16; ++i){
      int c = i*256 + t;
      gload_lds16(Wg + c*4, &Wl[b][c*4]);
    }
  };
  constexpr int NC = KK / 64;
  stage(0, 0);
  float a0 = 0.f, a1 = 0.f;
  int cur = 0;
  for (int c = 0; c < NC; ++c){
    __syncthreads();
    if (c + 1 < NC) stage(cur ^ 1, c + 1);
    #pragma unroll 16
    for (int k = 0; k < 64; ++k){
      float wv = Wl[cur][k*256 + t];
      a0 += xr[0][c*64 + k] * wv;
      a1 += xr[1][c*64 + k] * wv;
    }
    cur ^= 1;
  }
  zout[bt0*256 + t]     = a0;
  zout[(bt0+1)*256 + t] = a1;
}

// ---------------------------------------------------------------------------
// k_qmean: per b: hm = mean_t relu(bn4(z4[b,t,:])); q = hm @ qW + qb.
// ---------------------------------------------------------------------------
__global__ __launch_bounds__(256) void k_qmean(const float* __restrict__ z4,
                                               const float2* __restrict__ ss,
                                               const float* __restrict__ qW,
                                               const float* __restrict__ qb,
                                               float* __restrict__ q){
  __shared__ float Wl[2][64*256];
  __shared__ float hm[256];
  const int b = blockIdx.x, t = threadIdx.x;
  float2 sv = ss[t];
  float s = 0.f;
  #pragma unroll 8
  for (int tt = 0; tt < 64; ++tt)
    s += fmaxf(z4[((b<<6)+tt)*256 + t]*sv.x + sv.y, 0.f);
  hm[t] = s * (1.f/64.f);
  auto stage = [&](int bb, int c0){
    const float* Wg = qW + (size_t)c0 * 64 * 256;
    #pragma unroll
    for (int i = 0; i < 16; ++i){
      int c = i*256 + t;
      gload_lds16(Wg + c*4, &Wl[bb][c*4]);
    }
  };
  stage(0, 0);
  float a = 0.f;
  int cur = 0;
  for (int c = 0; c < 4; ++c){
    __syncthreads();
    if (c < 3) stage(cur ^ 1, c + 1);
    #pragma unroll 16
    for (int k = 0; k < 64; ++k)
      a += hm[c*64 + k] * Wl[cur][k*256 + t];
    cur ^= 1;
  }
  q[b*256 + t] = a + qb[t];
}

// ---------------------------------------------------------------------------
// k_att: per 2 bt rows: Hh = relu(bn4(z4)); kvec = Hh @ kW + kb;
//        s = dot(q_b, kvec)/16; out = Hh * sigmoid(s). grid 256 blocks.
// ---------------------------------------------------------------------------
__global__ __launch_bounds__(256) void k_att(const float* __restrict__ z4,
                                             const float2* __restrict__ ss,
                                             const float* __restrict__ kW,
                                             const float* __restrict__ kb,
                                             const float* __restrict__ q,
                                             float* __restrict__ out){
  __shared__ float Wl[2][64*256];
  __shared__ float xr[2][256];
  __shared__ float pw[2][4];
  const int bt0 = blockIdx.x * 2;
  const int b = bt0 >> 6;
  const int t = threadIdx.x;
  float2 sv = ss[t];
  xr[0][t] = fmaxf(z4[bt0*256 + t]*sv.x + sv.y, 0.f);
  xr[1][t] = fmaxf(z4[(bt0+1)*256 + t]*sv.x + sv.y, 0.f);
  auto stage = [&](int bb, int c0){
    const float* Wg = kW + (size_t)c0 * 64 * 256;
    #pragma unroll
    for (int i = 0; i < 16; ++i){
      int c = i*256 + t;
      gload_lds16(Wg + c*4, &Wl[bb][c*4]);
    }
  };
  stage(0, 0);
  float a0 = 0.f, a1 = 0.f;
  int cur = 0;
  for (int c = 0; c < 4; ++c){
    __syncthreads();
    if (c < 3) stage(cur ^ 1, c + 1);
    #pragma unroll 16
    for (int k = 0; k < 64; ++k){
      float wv = Wl[cur][k*256 + t];
      a0 += xr[0][c*64 + k] * wv;
      a1 += xr[1][c*64 + k] * wv;
    }
    cur ^= 1;
  }
  float qv = q[b*256 + t];
  float p0 = (a0 + kb[t]) * qv;
  float p1 = (a1 + kb[t]) * qv;
  #pragma unroll
  for (int o = 1; o < 64; o <<= 1){
    p0 += __shfl_xor(p0, o);
    p1 += __shfl_xor(p1, o);
  }
  if ((t & 63) == 0){ pw[0][t >> 6] = p0; pw[1][t >> 6] = p1; }
  __syncthreads();
  float s0 = (pw[0][0] + pw[0][1] + pw[0][2] + pw[0][3]) * (1.f/16.f);
  float s1 = (pw[1][0] + pw[1][1] + pw[1][2] + pw[1][3]) * (1.f/16.f);
  float g0 = 1.f / (1.f + __expf(-s0));
  float g1 = 1.f / (1.f + __expf(-s1));
  out[bt0*256 + t]     = xr[0][t] * g0;
  out[(bt0+1)*256 + t] = xr[1][t] * g1;
}

// ---------------------------------------------------------------------------
extern "C" void kernel_launch(void* const* d_in, const int* in_sizes, int n_in,
                              void* d_out, int out_size, void* d_ws, size_t ws_size,
                              hipStream_t stream){
  (void)in_sizes; (void)n_in; (void)out_size; (void)ws_size;
  const float* x    = (const float*)d_in[0];
  const float* e_s  = (const float*)d_in[1];
  const float* qW   = (const float*)d_in[2];
  const float* qb   = (const float*)d_in[3];
  const float* kW   = (const float*)d_in[4];
  const float* kb   = (const float*)d_in[5];
  const float* m1W  = (const float*)d_in[6];
  const float* m1g  = (const float*)d_in[8];
  const float* m1be = (const float*)d_in[9];
  const float* m2W  = (const float*)d_in[10];
  const float* m2g  = (const float*)d_in[12];
  const float* m2be = (const float*)d_in[13];
  const float* p1W  = (const float*)d_in[14];
  const float* p1g  = (const float*)d_in[16];
  const float* p1be = (const float*)d_in[17];
  const float* p2W  = (const float*)d_in[18];
  const float* p2g  = (const float*)d_in[20];
  const float* p2be = (const float*)d_in[21];
  // biases m1b,m2b,p1b,p2b (d_in[7,11,15,19]) cancel in BN — unused.

  char* ws = (char*)d_ws;
  unsigned short* WT = (unsigned short*)ws; ws += 33554432;
  unsigned short* fc = (unsigned short*)ws; ws += 67108864;
  float* P   = (float*)ws;  ws += 33554432;
  float* z1  = (float*)ws;  ws += 524288;
  float* z2  = (float*)ws;  ws += 524288;
  float* z3  = (float*)ws;  ws += 524288;
  float* z4  = (float*)ws;  ws += 524288;
  float2* s1 = (float2*)ws; ws += 2048;
  float2* s2 = (float2*)ws; ws += 2048;
  float2* s3 = (float2*)ws; ws += 2048;
  float2* s4 = (float2*)ws; ws += 2048;
  float* qv  = (float*)ws;  ws += 8192;
  float* out = (float*)d_out;

  k_wt    <<<dim3(1024, 4), 256, 0, stream>>>(m1W, WT);
  k_corr  <<<512, 256, 0, stream>>>(x, fc);
  k_gemm  <<<dim3(64, 4), 512, 0, stream>>>(fc, WT, P);
  k_reduce<<<128, 256, 0, stream>>>(P, z1);
  k_stats <<<256, 256, 0, stream>>>(z1, m1g, m1be, s1);
  k_sg<256,false><<<256, 256, 0, stream>>>(z1, s1, nullptr, m2W, z2);
  k_stats <<<256, 256, 0, stream>>>(z2, m2g, m2be, s2);
  k_sg<512,true> <<<256, 256, 0, stream>>>(z2, s2, e_s, p1W, z3);
  k_stats <<<256, 256, 0, stream>>>(z3, p1g, p1be, s3);
  k_sg<256,false><<<256, 256, 0, stream>>>(z3, s3, nullptr, p2W, z4);
  k_stats <<<256, 256, 0, stream>>>(z4, p2g, p2be, s4);
  k_qmean <<<8, 256, 0, stream>>>(z4, s4, qW, qb, qv);
  k_att   <<<256, 256, 0, stream>>>(z4, s4, kW, kb, qv, out);
}